// Round 1
// baseline (53.178 us; speedup 1.0000x reference)
//
#include <hip/hip_runtime.h>
#include <math.h>

#define GRID_G 16
#define K_SLOPE 10.0f
#define LOG2E 1.4426950408889634f

__global__ __launch_bounds__(256) void piou_pairwise_kernel(
    const float* __restrict__ P,   // [N,5] cx,cy,w,h,theta
    const float* __restrict__ T,   // [M,5]
    float* __restrict__ out,       // [N,M]
    int N, int M)
{
    int t = blockIdx.x * blockDim.x + threadIdx.x;
    if (t >= N * M) return;
    int i = t / M;          // wave-uniform for M=512, block=256
    int j = t - i * M;

    // Load box params (P row is block-uniform -> scalarized by compiler)
    float cxp = P[5*i+0], cyp = P[5*i+1], wp = P[5*i+2], hp = P[5*i+3], thp = P[5*i+4];
    float cxt = T[5*j+0], cyt = T[5*j+1], wt = T[5*j+2], ht = T[5*j+3], tht = T[5*j+4];

    // Pair-invariant trig (precise; amortized over 256 samples)
    float sp, cp, st, ct;
    sincosf(thp, &sp, &cp);
    sincosf(tht, &st, &ct);

    // AABBs
    float acp = fabsf(cp), asp = fabsf(sp);
    float hwp = 0.5f * (wp * acp + hp * asp);
    float hhp = 0.5f * (wp * asp + hp * acp);
    float act = fabsf(ct), ast = fabsf(st);
    float hwt = 0.5f * (wt * act + ht * ast);
    float hht = 0.5f * (wt * ast + ht * act);

    // Joint bounding region
    float xmin = fminf(cxp - hwp, cxt - hwt);
    float xmax = fmaxf(cxp + hwp, cxt + hwt);
    float ymin = fminf(cyp - hhp, cyt - hht);
    float ymax = fmaxf(cyp + hhp, cyt + hht);

    float dxr = xmax - xmin;
    float dyr = ymax - ymin;
    const float inv_g = 1.0f / (float)GRID_G;
    float stepx = dxr * inv_g;

    // sigmoid(k*(0.5*s - d)) = 1/(1 + exp2(K2*d - K2*0.5*s)), K2 = k*log2(e)
    const float K2 = K_SLOPE * LOG2E;
    float cwp = -0.5f * K2 * wp;
    float chp = -0.5f * K2 * hp;
    float cwt = -0.5f * K2 * wt;
    float cht = -0.5f * K2 * ht;

    // per-gx increments of rotated coordinates
    float iw1 = stepx * cp, ih1 = -stepx * sp;
    float iw2 = stepx * ct, ih2 = -stepx * st;

    float px0 = fmaf(dxr, 0.5f * inv_g, xmin);

    float s1 = 0.0f, s2 = 0.0f, s12 = 0.0f;

    for (int gy = 0; gy < GRID_G; ++gy) {
        float py  = fmaf(dyr, ((float)gy + 0.5f) * inv_g, ymin);
        float dyp = py - cyp, dyt = py - cyt;
        float dxp = px0 - cxp, dxt = px0 - cxt;

        // rotated coords at gx=0
        float rw1_0 =  dxp * cp + dyp * sp;
        float rh1_0 = -dxp * sp + dyp * cp;
        float rw2_0 =  dxt * ct + dyt * st;
        float rh2_0 = -dxt * st + dyt * ct;

        #pragma unroll
        for (int gx = 0; gx < GRID_G; ++gx) {
            float gxf = (float)gx;
            float rw1 = fmaf(gxf, iw1, rw1_0);
            float rh1 = fmaf(gxf, ih1, rh1_0);
            float rw2 = fmaf(gxf, iw2, rw2_0);
            float rh2 = fmaf(gxf, ih2, rh2_0);

            float ea1 = __builtin_amdgcn_exp2f(fmaf(K2, fabsf(rw1), cwp));
            float eb1 = __builtin_amdgcn_exp2f(fmaf(K2, fabsf(rh1), chp));
            float ea2 = __builtin_amdgcn_exp2f(fmaf(K2, fabsf(rw2), cwt));
            float eb2 = __builtin_amdgcn_exp2f(fmaf(K2, fabsf(rh2), cht));

            float d1 = (1.0f + ea1) * (1.0f + eb1);
            float d2 = (1.0f + ea2) * (1.0f + eb2);
            float r1 = __builtin_amdgcn_rcpf(d1);   // F1
            float r2 = __builtin_amdgcn_rcpf(d2);   // F2

            s1  += r1;
            s2  += r2;
            s12  = fmaf(r1, r2, s12);
        }
    }

    out[t] = s12 / (s1 + s2 - s12 + 1e-6f);
}

extern "C" void kernel_launch(void* const* d_in, const int* in_sizes, int n_in,
                              void* d_out, int out_size, void* d_ws, size_t ws_size,
                              hipStream_t stream) {
    const float* P = (const float*)d_in[0];
    const float* T = (const float*)d_in[1];
    // d_in[2] is grid (=16), baked in as GRID_G
    float* out = (float*)d_out;

    int N = in_sizes[0] / 5;
    int M = in_sizes[1] / 5;
    int total = N * M;
    int block = 256;
    int grid = (total + block - 1) / block;
    piou_pairwise_kernel<<<grid, block, 0, stream>>>(P, T, out, N, M);
}

// Round 2
// 48.904 us; speedup vs baseline: 1.0874x; 1.0874x over previous
//
#include <hip/hip_runtime.h>
#include <math.h>

#define GRID_G 16
#define SPLIT  4            // threads per pair (each does GRID_G/SPLIT gy rows)
#define K_SLOPE 10.0f
#define LOG2E 1.4426950408889634f

typedef float v2f __attribute__((ext_vector_type(2)));

static __device__ __forceinline__ v2f vfma(v2f a, v2f b, v2f c) {
    return __builtin_elementwise_fma(a, b, c);
}
static __device__ __forceinline__ v2f vexp2(v2f a) {
    return (v2f){__builtin_amdgcn_exp2f(a.x), __builtin_amdgcn_exp2f(a.y)};
}
static __device__ __forceinline__ v2f vrcp(v2f a) {
    return (v2f){__builtin_amdgcn_rcpf(a.x), __builtin_amdgcn_rcpf(a.y)};
}
// arg = K2*|rw| + c, per component (VOP3 v_fma_f32 with abs modifier)
static __device__ __forceinline__ v2f vargabs(v2f rw, float K2, float c) {
    return (v2f){fmaf(K2, fabsf(rw.x), c), fmaf(K2, fabsf(rw.y), c)};
}

__global__ __launch_bounds__(256) void piou_pairwise_kernel(
    const float* __restrict__ P,   // [N,5] cx,cy,w,h,theta
    const float* __restrict__ T,   // [M,5]
    float* __restrict__ out,       // [N,M]
    int N, int M)
{
    int gtid = blockIdx.x * blockDim.x + threadIdx.x;
    int pair = gtid >> 2;          // SPLIT = 4
    int sub  = gtid & 3;
    if (pair >= N * M) return;
    int i = pair / M;
    int j = pair - i * M;

    float cxp = P[5*i+0], cyp = P[5*i+1], wp = P[5*i+2], hp = P[5*i+3], thp = P[5*i+4];
    float cxt = T[5*j+0], cyt = T[5*j+1], wt = T[5*j+2], ht = T[5*j+3], tht = T[5*j+4];

    float sp, cp, st, ct;
    sincosf(thp, &sp, &cp);
    sincosf(tht, &st, &ct);

    // AABBs and joint region
    float acp = fabsf(cp), asp = fabsf(sp);
    float hwp = 0.5f * (wp * acp + hp * asp);
    float hhp = 0.5f * (wp * asp + hp * acp);
    float act = fabsf(ct), ast = fabsf(st);
    float hwt = 0.5f * (wt * act + ht * ast);
    float hht = 0.5f * (wt * ast + ht * act);

    float xmin = fminf(cxp - hwp, cxt - hwt);
    float xmax = fmaxf(cxp + hwp, cxt + hwt);
    float ymin = fminf(cyp - hhp, cyt - hht);
    float ymax = fmaxf(cyp + hhp, cyt + hht);

    float dxr = xmax - xmin;
    float dyr = ymax - ymin;
    const float inv_g = 1.0f / (float)GRID_G;
    float stepx = dxr * inv_g;

    const float K2 = K_SLOPE * LOG2E;
    float cwp = -0.5f * K2 * wp;
    float chp = -0.5f * K2 * hp;
    float cwt = -0.5f * K2 * wt;
    float cht = -0.5f * K2 * ht;

    // per-gx increments of rotated coordinates
    float iw1 = stepx * cp, ih1 = -stepx * sp;
    float iw2 = stepx * ct, ih2 = -stepx * st;

    float px0 = fmaf(dxr, 0.5f * inv_g, xmin);
    float dxp = px0 - cxp, dxt = px0 - cxt;

    v2f s1v  = (v2f){0.f, 0.f};
    v2f s2v  = (v2f){0.f, 0.f};
    v2f s12v = (v2f){0.f, 0.f};

    #pragma unroll
    for (int r = 0; r < GRID_G / SPLIT; ++r) {
        int gy = sub * (GRID_G / SPLIT) + r;
        float py  = fmaf(dyr, ((float)gy + 0.5f) * inv_g, ymin);
        float dyp = py - cyp, dyt = py - cyt;

        // rotated coords at gx=0
        float rw1_0 =  dxp * cp + dyp * sp;
        float rh1_0 = -dxp * sp + dyp * cp;
        float rw2_0 =  dxt * ct + dyt * st;
        float rh2_0 = -dxt * st + dyt * ct;

        #pragma unroll
        for (int gp = 0; gp < GRID_G / 2; ++gp) {
            v2f gxv = (v2f){(float)(2*gp), (float)(2*gp + 1)};

            v2f rw1 = vfma(gxv, (v2f)(iw1), (v2f)(rw1_0));
            v2f rh1 = vfma(gxv, (v2f)(ih1), (v2f)(rh1_0));
            v2f rw2 = vfma(gxv, (v2f)(iw2), (v2f)(rw2_0));
            v2f rh2 = vfma(gxv, (v2f)(ih2), (v2f)(rh2_0));

            v2f e1w = vexp2(vargabs(rw1, K2, cwp));
            v2f e1h = vexp2(vargabs(rh1, K2, chp));
            v2f e2w = vexp2(vargabs(rw2, K2, cwt));
            v2f e2h = vexp2(vargabs(rh2, K2, cht));

            // d = (1+ew)(1+eh); inf-safe (all factors >= 1, no 0*inf)
            v2f d1 = (e1w + 1.0f) * (e1h + 1.0f);
            v2f d2 = (e2w + 1.0f) * (e2h + 1.0f);

            v2f r1 = vrcp(d1);   // F1 for two gx samples
            v2f r2 = vrcp(d2);   // F2

            s1v  = s1v + r1;
            s2v  = s2v + r2;
            s12v = vfma(r1, r2, s12v);
        }
    }

    float s1  = s1v.x + s1v.y;
    float s2  = s2v.x + s2v.y;
    float s12 = s12v.x + s12v.y;

    // combine the SPLIT partial sums (lanes of the same pair are adjacent)
    #pragma unroll
    for (int m = 1; m < SPLIT; m <<= 1) {
        s1  += __shfl_xor(s1,  m);
        s2  += __shfl_xor(s2,  m);
        s12 += __shfl_xor(s12, m);
    }

    if (sub == 0)
        out[pair] = s12 / (s1 + s2 - s12 + 1e-6f);
}

extern "C" void kernel_launch(void* const* d_in, const int* in_sizes, int n_in,
                              void* d_out, int out_size, void* d_ws, size_t ws_size,
                              hipStream_t stream) {
    const float* P = (const float*)d_in[0];
    const float* T = (const float*)d_in[1];
    float* out = (float*)d_out;

    int N = in_sizes[0] / 5;
    int M = in_sizes[1] / 5;
    long long total = (long long)N * M * SPLIT;
    int block = 256;
    int grid = (int)((total + block - 1) / block);
    piou_pairwise_kernel<<<grid, block, 0, stream>>>(P, T, out, N, M);
}